// Round 10
// baseline (630.346 us; speedup 1.0000x reference)
//
#include <hip/hip_runtime.h>

// LSTMDecoder: B=4096, LATENT=128, SEQ=512, HID=32, OUT=64. f32 in/out.
// Round 17: 4-wave block, 2 cells/lane — transc invariant kept, LDS traffic
// and barrier width HALVED.
//
//  - Accounting (r16 @ ~1090 cyc/step): transc 256 (invariant: 16 instr/SIMD)
//    + VALU ~100 + LDS pipe ~230 (8 waves x 5 ds-ops) + read lat 130 + 8-wave
//    barrier skew. r14b showed extra waves double LDS traffic and cancel
//    overlap gains -> shrink the LDS/barrier block instead.
//  - 4 waves x 64 lanes x 2 cells = 512 cells = 16 rows x 32 cells: the same
//    transc issue/SIMD (16 instr) now from ONE wave/SIMD, but:
//      * exchange write = ONE packed b32/lane (2 f16 halves) at dword w of a
//        padded 20 B row (bank (5l+w)%32 = 2-way, free)
//      * 4x b32 reads land DIRECTLY in B-frag slot order (dword d halves m ->
//        slot 2d+m = required layout)
//      * ds-ops/CU/step: 40 -> 20; barrier syncs 4 waves, not 8
//  - Gates: r13's verified 2-cells/lane structure: two fused MFMAs, Atil_m
//    row d = W_hh row 32*(d&3)+16s+4*(d>>2)+2p0+m, scale-folded.
//  - Act: r16's 8-transc/cell fused form (both sig*tanh pairs rcp-fused,
//    overflow-clamped).
//  - Proj: every wave owns tile p=w, every step, r11's deferred placement
//    (proj h_t -> y[t-1] after gate-MFMA issue; tail y[511] after loop).
//  - Grid: 256 blocks x 256 threads (1 block/CU, 1 wave/SIMD).

#define B_SZ   4096
#define LATENT 128
#define SEQ    512
#define HID    32
#define OUT_N  64
#define ROWS   16
#define LSW    40   // h0 staging row stride in halves (80 B rows)
#define HXD    5    // hx row stride in dwords (20 B rows)

typedef _Float16 f16x8 __attribute__((ext_vector_type(8)));
typedef _Float16 f16x4 __attribute__((ext_vector_type(4)));
typedef float    f32x4 __attribute__((ext_vector_type(4)));

__device__ __forceinline__ float fexp2(float x) { return __builtin_amdgcn_exp2f(x); }
__device__ __forceinline__ float frcp(float x)  { return __builtin_amdgcn_rcpf(x); }
__device__ __forceinline__ void lds_barrier() {
    asm volatile("s_waitcnt lgkmcnt(0)\n\ts_barrier" ::: "memory");
}

__global__ __launch_bounds__(256)
void lstm_q17(const float* __restrict__ z,
              const float* __restrict__ init_W,
              const float* __restrict__ init_b,
              const float* __restrict__ W_hh,
              const float* __restrict__ b_ih,
              const float* __restrict__ b_hh,
              const float* __restrict__ out_W,
              const float* __restrict__ out_b,
              float* __restrict__ y)
{
    __shared__ __align__(16) _Float16 hst[ROWS * LSW];
    __shared__ __align__(4) unsigned hx[2][64][HXD];   // [par][lane][dword]

    const int tid  = threadIdx.x;
    const int w    = tid >> 6;          // wave 0..3
    const int lane = tid & 63;
    const int n_   = lane & 15;         // batch row within tile (MFMA col)
    const int q    = lane >> 4;         // quad group (MFMA row group)
    const int s_   = w >> 1;            // cell half
    const int p0   = w & 1;             // cell pair within quad
    const int rbase = blockIdx.x * ROWS;

    const float NL2E  = -1.44269504088896341f;   // -log2(e)
    const float P2L2E =  2.88539008177792681f;   // +2*log2(e)

    // ---- two fused-gate A-frags (r13 rec-wave structure, verified) ----
    f16x8 wf0, wf1;
    f32x4 bacc0, bacc1;
#pragma unroll
    for (int m = 0; m < 2; m++) {
        const int arow = 32 * (n_ & 3) + 16 * s_ + 4 * (n_ >> 2) + 2 * p0 + m;
        const float asc = ((n_ & 3) == 2) ? P2L2E : NL2E;
        const float* wrow = W_hh + (size_t)arow * HID;
        f16x8 v;
#pragma unroll
        for (int rr = 0; rr < 4; rr++) {
            v[rr]     = (_Float16)(asc * wrow[4 * q + rr]);
            v[4 + rr] = (_Float16)(asc * wrow[16 + 4 * q + rr]);
        }
        f32x4 b;
#pragma unroll
        for (int r = 0; r < 4; r++) {
            const int G = 32 * r + 16 * s_ + 4 * q + 2 * p0 + m;
            const float bsc = (r == 2) ? P2L2E : NL2E;
            b[r] = bsc * (b_ih[G] + b_hh[G]);
        }
        if (m == 0) { wf0 = v; bacc0 = b; } else { wf1 = v; bacc1 = b; }
    }

    // ---- proj A-frag: tile p = w ----
    f16x8 owf;
    f32x4 oacc;
    {
        const int p = w;
        const float* row = out_W + (size_t)(16 * p + n_) * HID;
#pragma unroll
        for (int rr = 0; rr < 4; rr++) {
            owf[rr]     = (_Float16)row[4 * q + rr];
            owf[4 + rr] = (_Float16)row[16 + 4 * q + rr];
        }
#pragma unroll
        for (int r = 0; r < 4; r++) oacc[r] = out_b[16 * p + 4 * q + r];
    }

    // ---- h0 = z @ init_W^T + init_b (2 cells per thread: 256 x 2 = 512) ----
    {
        int m = tid >> 4, j0 = tid & 15;
        const float4* zp = (const float4*)(z + (size_t)(rbase + m) * LATENT);
#pragma unroll
        for (int half = 0; half < 2; half++) {
            const int j = j0 + 16 * half;
            const float4* wp = (const float4*)(init_W + (size_t)j * LATENT);
            float acc = init_b[j];
#pragma unroll
            for (int k = 0; k < LATENT / 4; k++) {
                float4 a4 = zp[k], b4 = wp[k];
                acc = fmaf(a4.x, b4.x, acc); acc = fmaf(a4.y, b4.y, acc);
                acc = fmaf(a4.z, b4.z, acc); acc = fmaf(a4.w, b4.w, acc);
            }
            hst[m * LSW + j] = (_Float16)acc;
        }
    }
    __syncthreads();

    // initial fragment: slot 4s'+rr <- h0[n_][16s'+4q+rr]
    f16x8 a;
    {
        f16x4 lo = *(const f16x4*)&hst[n_ * LSW + 4 * q];
        f16x4 hi = *(const f16x4*)&hst[n_ * LSW + 4 * q + 16];
#pragma unroll
        for (int r = 0; r < 4; r++) { a[r] = lo[r]; a[4 + r] = hi[r]; }
    }

    float cs0 = 0.f, cs1 = 0.f;   // 2log2e-scaled cell states (cells m=0,1)

    float* yb = y + (size_t)(rbase + n_) * SEQ * OUT_N + 16 * w + 4 * q;

    for (int t = 0; t < SEQ; t += 4) {
#pragma unroll
        for (int u = 0; u < 4; u++) {
            const int par = u & 1;
            // ---- gates: 2 fused MFMAs (reg r = gate r of cell m) ----
            f32x4 ac0 = __builtin_amdgcn_mfma_f32_16x16x32_f16(wf0, a, bacc0, 0, 0, 0);
            f32x4 ac1 = __builtin_amdgcn_mfma_f32_16x16x32_f16(wf1, a, bacc1, 0, 0, 0);

            // ---- deferred projection: a = h_t, store y[t-1] (every wave) ----
            {
                f32x4 py = __builtin_amdgcn_mfma_f32_16x16x32_f16(owf, a, oacc, 0, 0, 0);
                if (t + u) *(f32x4*)(yb + (size_t)(t + u - 1) * OUT_N) = py;
            }

            // ---- activation: 8 transc/cell, both cells (r16 fused form) ----
            union { _Float16 h[2]; unsigned u32; } cv;
            {
                float Fi  = fexp2(ac0[0]);
                float Ff  = fexp2(ac0[1]);
                float Eg  = fexp2(ac0[2]);
                float Fo  = fexp2(ac0[3]);
                float rig = frcp((1.f + Fi) * (1.f + Eg));
                float tg  = fmaf(P2L2E, Eg, -P2L2E);
                float ig  = tg * rig;
                float gf  = frcp(1.f + Ff);
                float csn = fmaf(gf, cs0, ig);
                cs0 = csn;
                float Ecs = fexp2(fminf(csn, 126.f));
                float rd  = frcp((1.f + Fo) * (1.f + Ecs));
                cv.h[0] = (_Float16)((Ecs - 1.f) * rd);
            }
            {
                float Fi  = fexp2(ac1[0]);
                float Ff  = fexp2(ac1[1]);
                float Eg  = fexp2(ac1[2]);
                float Fo  = fexp2(ac1[3]);
                float rig = frcp((1.f + Fi) * (1.f + Eg));
                float tg  = fmaf(P2L2E, Eg, -P2L2E);
                float ig  = tg * rig;
                float gf  = frcp(1.f + Ff);
                float csn = fmaf(gf, cs1, ig);
                cs1 = csn;
                float Ecs = fexp2(fminf(csn, 126.f));
                float rd  = frcp((1.f + Fo) * (1.f + Ecs));
                cv.h[1] = (_Float16)((Ecs - 1.f) * rd);
            }
            // ---- ONE packed b32 write at dword w (2-way bank, free) ----
            hx[par][lane][w] = cv.u32;

            lds_barrier();

            // ---- rebuild fragment: 4x b32, conflict-free, direct slot order ----
            {
                union { unsigned uu[4]; f16x8 v; } ua;
                const unsigned* rp = &hx[par][lane][0];
                ua.uu[0] = rp[0]; ua.uu[1] = rp[1]; ua.uu[2] = rp[2]; ua.uu[3] = rp[3];
                a = ua.v;
            }
        }
    }

    // ---- tail: y[511] = proj(h_512) ----
    {
        f32x4 py = __builtin_amdgcn_mfma_f32_16x16x32_f16(owf, a, oacc, 0, 0, 0);
        *(f32x4*)(yb + (size_t)(SEQ - 1) * OUT_N) = py;
    }
}

extern "C" void kernel_launch(void* const* d_in, const int* in_sizes, int n_in,
                              void* d_out, int out_size, void* d_ws, size_t ws_size,
                              hipStream_t stream) {
    const float* z      = (const float*)d_in[0];
    const float* init_W = (const float*)d_in[1];
    const float* init_b = (const float*)d_in[2];
    // d_in[3] = W_ih: unused (x input is all zeros; only biases survive)
    const float* W_hh   = (const float*)d_in[4];
    const float* b_ih   = (const float*)d_in[5];
    const float* b_hh   = (const float*)d_in[6];
    const float* out_W  = (const float*)d_in[7];
    const float* out_b  = (const float*)d_in[8];
    float* yout = (float*)d_out;

    lstm_q17<<<B_SZ / ROWS, 256, 0, stream>>>(z, init_W, init_b, W_hh, b_ih, b_hh,
                                              out_W, out_b, yout);
}

// Round 11
// 595.747 us; speedup vs baseline: 1.0581x; 1.0581x over previous
//
#include <hip/hip_runtime.h>

// LSTMDecoder: B=4096, LATENT=128, SEQ=512, HID=32, OUT=64. f32 in/out.
// Round 18: de-phase the SIMD wave pair (single-variable change vs r16).
//
//  - r16 defect: SIMD = w&3 hosts waves {k, k+4}, and jj = w&1 gives both the
//    SAME jj -> the two co-resident waves are workload-identical clones. Proj
//    steps: both project; other steps: neither. Transc bursts, MFMA waits and
//    ds_read stalls coincide -> latency bubbles perfectly aligned, wall ~1115
//    cyc/step vs ~450 issue.
//  - FIX: jj = w>>2, r_ = w&3. SIMD k now hosts one jj=0 and one jj=1 wave.
//    Every step exactly ONE of the pair does proj MFMA+store (jj==par) while
//    the other goes straight to act -> phases staggered ~40 cyc, proj issue
//    fills the partner's transc/rcp latency bubbles; proj/store traffic is
//    uniform per step instead of bursty.
//  - Everything else IDENTICAL to r16 (best, 578.3): fused single gate MFMA
//    (permuted Atil, scale-folded -log2e/+2log2e), 8-transc fused act,
//    padded hx (20 B rows), ONE lgkm barrier/step, 4x b32 rebuild,
//    deferred jj==par proj.

#define B_SZ   4096
#define LATENT 128
#define SEQ    512
#define HID    32
#define OUT_N  64
#define ROWS   16
#define LSW    40   // h0 staging row stride in halves (80 B rows)
#define HXW    10   // hx row stride in halves (20 B rows)

typedef _Float16 f16x8 __attribute__((ext_vector_type(8)));
typedef _Float16 f16x4 __attribute__((ext_vector_type(4)));
typedef float    f32x4 __attribute__((ext_vector_type(4)));

__device__ __forceinline__ float fexp2(float x) { return __builtin_amdgcn_exp2f(x); }
__device__ __forceinline__ float frcp(float x)  { return __builtin_amdgcn_rcpf(x); }
__device__ __forceinline__ void lds_barrier() {
    asm volatile("s_waitcnt lgkmcnt(0)\n\ts_barrier" ::: "memory");
}

__global__ __launch_bounds__(512)
void lstm_tr18(const float* __restrict__ z,
               const float* __restrict__ init_W,
               const float* __restrict__ init_b,
               const float* __restrict__ W_hh,
               const float* __restrict__ b_ih,
               const float* __restrict__ b_hh,
               const float* __restrict__ out_W,
               const float* __restrict__ out_b,
               float* __restrict__ y)
{
    __shared__ __align__(16) _Float16 hst[ROWS * LSW];
    __shared__ __align__(4) unsigned short hx[2][64][HXW];  // 20 B rows

    const int tid  = threadIdx.x;
    const int w    = tid >> 6;          // wave 0..7
    const int lane = tid & 63;
    const int n_   = lane & 15;         // batch row within tile
    const int kb   = lane >> 4;         // k-group / quad group
    const int jj   = w >> 2;            // cell half  (REMAP: was w & 1)
    const int r_   = w & 3;             // cell sub-index (REMAP: was w >> 1)
    const int rbase = blockIdx.x * ROWS;

    const float NL2E  = -1.44269504088896341f;   // -log2(e)
    const float P2L2E =  2.88539008177792681f;   // +2*log2(e)

    // ---- fused gate A-frag: Atil row d = W_hh row 32*(d&3)+16jj+4*(d>>2)+r_ ----
    f16x8 wf1;
    f32x4 bacc1;
    {
        const int arow = 32 * (n_ & 3) + 16 * jj + 4 * (n_ >> 2) + r_;
        const float asc = ((n_ & 3) == 2) ? P2L2E : NL2E;
        const float* wrow = W_hh + (size_t)arow * HID;
#pragma unroll
        for (int rr = 0; rr < 4; rr++) {
            wf1[rr]     = (_Float16)(asc * wrow[4 * kb + rr]);
            wf1[4 + rr] = (_Float16)(asc * wrow[16 + 4 * kb + rr]);
        }
#pragma unroll
        for (int r = 0; r < 4; r++) {
            const int G = 32 * r + 16 * jj + 4 * kb + r_;
            const float bsc = (r == 2) ? P2L2E : NL2E;
            bacc1[r] = bsc * (b_ih[G] + b_hh[G]);
        }
    }

    // ---- proj A-frag (each wave owns tile p=r_; both jj groups keep a copy) ----
    f16x8 owf;
    f32x4 oacc;
    {
        const int p = r_;
        const float* row = out_W + (size_t)(16 * p + n_) * HID;
#pragma unroll
        for (int rr = 0; rr < 4; rr++) {
            owf[rr]     = (_Float16)row[4 * kb + rr];
            owf[4 + rr] = (_Float16)row[4 * kb + 16 + rr];
        }
#pragma unroll
        for (int r = 0; r < 4; r++) oacc[r] = out_b[16 * p + 4 * kb + r];
    }

    // ---- h0 = z @ init_W^T + init_b (one cell per thread: 512 = 16x32) ----
    {
        int m = tid >> 5, j = tid & 31;
        const float4* zp = (const float4*)(z + (size_t)(rbase + m) * LATENT);
        const float4* wp = (const float4*)(init_W + (size_t)j * LATENT);
        float acc = init_b[j];
#pragma unroll
        for (int k = 0; k < LATENT / 4; k++) {
            float4 a4 = zp[k], b4 = wp[k];
            acc = fmaf(a4.x, b4.x, acc); acc = fmaf(a4.y, b4.y, acc);
            acc = fmaf(a4.z, b4.z, acc); acc = fmaf(a4.w, b4.w, acc);
        }
        hst[m * LSW + j] = (_Float16)acc;
    }
    __syncthreads();

    // initial fragment: slot 4jj'+rr <- h0[n_][4kb+rr / 16+4kb+rr]
    f16x8 a;
    {
        f16x4 lo = *(const f16x4*)&hst[n_ * LSW + 4 * kb];
        f16x4 hi = *(const f16x4*)&hst[n_ * LSW + 4 * kb + 16];
#pragma unroll
        for (int r = 0; r < 4; r++) { a[r] = lo[r]; a[4 + r] = hi[r]; }
    }

    float cs = 0.f;   // 2log2e-scaled cell state of cell 4kb+16jj+r_, row n_

    float* yb = y + (size_t)(rbase + n_) * SEQ * OUT_N + 16 * r_ + 4 * kb;

    for (int t = 0; t < SEQ; t += 4) {
#pragma unroll
        for (int u = 0; u < 4; u++) {
            const int par = u & 1;
            // ---- gate MFMA first: issues the moment the exchange read lands ----
            f32x4 acc = __builtin_amdgcn_mfma_f32_16x16x32_f16(wf1, a, bacc1, 0, 0, 0);

            // ---- deferred projection: a = h_s, store y[s-1] (group jj==par) ----
            if (jj == par) {
                f32x4 py = __builtin_amdgcn_mfma_f32_16x16x32_f16(owf, a, oacc, 0, 0, 0);
                if (t + u) *(f32x4*)(yb + (size_t)(t + u - 1) * OUT_N) = py;
            }

            // ---- activation: 8 transc (both sig*tanh pairs rcp-fused) ----
            {
                float Fi  = fexp2(acc[0]);                  // e^{-x_i}
                float Ff  = fexp2(acc[1]);                  // e^{-x_f}
                float Eg  = fexp2(acc[2]);                  // e^{2 x_g}
                float Fo  = fexp2(acc[3]);                  // e^{-x_o}
                float rig = frcp((1.f + Fi) * (1.f + Eg));
                float tg  = fmaf(P2L2E, Eg, -P2L2E);        // 2L*(Eg-1)
                float ig  = tg * rig;                       // 2L*sig(i)*tanh(g)
                float gf  = frcp(1.f + Ff);                 // sig(f)
                float csn = fmaf(gf, cs, ig);               // 2L-scaled c
                cs = csn;
                float Ecs = fexp2(fminf(csn, 126.f));       // e^{2c}, overflow-safe
                float rd  = frcp((1.f + Fo) * (1.f + Ecs));
                float hh  = (Ecs - 1.f) * rd;               // sig(o)*tanh(c)
                union { _Float16 h; unsigned short u16; } cv;
                cv.h = (_Float16)hh;
                hx[par][lane][4 * jj + r_] = cv.u16;
            }
            lds_barrier();

            // ---- rebuild fragment: 4x ds_read_b32, conflict-free, slot order ----
            {
                union { unsigned uu[4]; f16x8 v; } ua;
                const unsigned* rp = (const unsigned*)&hx[par][lane][0];
                ua.uu[0] = rp[0]; ua.uu[1] = rp[1]; ua.uu[2] = rp[2]; ua.uu[3] = rp[3];
                a = ua.v;
            }
        }
    }

    // ---- tail: y[511] = proj(h_512) (jj==0 group; par of step 512 is 0) ----
    if (jj == 0) {
        f32x4 py = __builtin_amdgcn_mfma_f32_16x16x32_f16(owf, a, oacc, 0, 0, 0);
        *(f32x4*)(yb + (size_t)(SEQ - 1) * OUT_N) = py;
    }
}

extern "C" void kernel_launch(void* const* d_in, const int* in_sizes, int n_in,
                              void* d_out, int out_size, void* d_ws, size_t ws_size,
                              hipStream_t stream) {
    const float* z      = (const float*)d_in[0];
    const float* init_W = (const float*)d_in[1];
    const float* init_b = (const float*)d_in[2];
    // d_in[3] = W_ih: unused (x input is all zeros; only biases survive)
    const float* W_hh   = (const float*)d_in[4];
    const float* b_ih   = (const float*)d_in[5];
    const float* b_hh   = (const float*)d_in[6];
    const float* out_W  = (const float*)d_in[7];
    const float* out_b  = (const float*)d_in[8];
    float* yout = (float*)d_out;

    lstm_tr18<<<B_SZ / ROWS, 512, 0, stream>>>(z, init_W, init_b, W_hh, b_ih, b_hh,
                                               out_W, out_b, yout);
}

// Round 14
// 580.538 us; speedup vs baseline: 1.0858x; 1.0262x over previous
//
#include <hip/hip_runtime.h>

// LSTMDecoder: B=4096, LATENT=128, SEQ=512, HID=32, OUT=64. f32 in/out.
// Round 20: third submission of the measured best (r16, 578.3 us on HW).
// r19/r19b were broker/container failures ("container failed twice"), not
// kernel faults — this source's compute path is byte-identical to r16 which
// passed in Round 8. Symbol renamed to dodge any stale-artifact caching.
//
//  - Structural sweep complete; all alternatives measured and worse:
//    r12 (+210, wave-local), r13 (+20, specialization), r14b (+66, 2 barrier
//    domains), r17 (+52, 4-wave), r18 (+17, de-phased pairs). The r16 point —
//    8 waves, 1 cell/lane, clone-symmetric SIMD pairs, 1 barrier/step — is
//    the optimum of this decomposition; clone alignment on the issue port is
//    load-bearing (r18).
//  - Content is minimal: fused single gate MFMA (permuted Atil, scale-folded
//    -log2e/+2log2e), 8-transc fused activation (both sig*tanh pairs
//    rcp-fused, overflow-clamped), padded hx (20 B rows, 2-way banks = free),
//    4x conflict-free b32 rebuild, deferred jj==par projection.
//  - Per-SIMD/step issue ~300 cyc vs ~1090 wall; the residue is exchange
//    latency + barrier resync, which five structural experiments failed to
//    compress. Transc floor (invariant 16 instr/SIMD/step) = 107 us; kernel
//    ~233 us + ~345 us harness fill = dur_us ~578.

#define B_SZ   4096
#define LATENT 128
#define SEQ    512
#define HID    32
#define OUT_N  64
#define ROWS   16
#define LSW    40   // h0 staging row stride in halves (80 B rows)
#define HXW    10   // hx row stride in halves (20 B rows)

typedef _Float16 f16x8 __attribute__((ext_vector_type(8)));
typedef _Float16 f16x4 __attribute__((ext_vector_type(4)));
typedef float    f32x4 __attribute__((ext_vector_type(4)));

__device__ __forceinline__ float fexp2(float x) { return __builtin_amdgcn_exp2f(x); }
__device__ __forceinline__ float frcp(float x)  { return __builtin_amdgcn_rcpf(x); }
__device__ __forceinline__ void lds_barrier() {
    asm volatile("s_waitcnt lgkmcnt(0)\n\ts_barrier" ::: "memory");
}

__global__ __launch_bounds__(512)
void lstm_tr20(const float* __restrict__ z,
               const float* __restrict__ init_W,
               const float* __restrict__ init_b,
               const float* __restrict__ W_hh,
               const float* __restrict__ b_ih,
               const float* __restrict__ b_hh,
               const float* __restrict__ out_W,
               const float* __restrict__ out_b,
               float* __restrict__ y)
{
    __shared__ __align__(16) _Float16 hst[ROWS * LSW];
    __shared__ __align__(4) unsigned short hx[2][64][HXW];  // 20 B rows

    const int tid  = threadIdx.x;
    const int w    = tid >> 6;          // wave 0..7
    const int lane = tid & 63;
    const int n_   = lane & 15;         // batch row within tile
    const int kb   = lane >> 4;         // k-group / quad group
    const int jj   = w & 1;             // cell half
    const int r_   = w >> 1;            // cell sub-index this wave activates (0..3)
    const int rbase = blockIdx.x * ROWS;

    const float NL2E  = -1.44269504088896341f;   // -log2(e)
    const float P2L2E =  2.88539008177792681f;   // +2*log2(e)

    // ---- fused gate A-frag: Atil row d = W_hh row 32*(d&3)+16jj+4*(d>>2)+r_ ----
    f16x8 wf1;
    f32x4 bacc1;
    {
        const int arow = 32 * (n_ & 3) + 16 * jj + 4 * (n_ >> 2) + r_;
        const float asc = ((n_ & 3) == 2) ? P2L2E : NL2E;
        const float* wrow = W_hh + (size_t)arow * HID;
#pragma unroll
        for (int rr = 0; rr < 4; rr++) {
            wf1[rr]     = (_Float16)(asc * wrow[4 * kb + rr]);
            wf1[4 + rr] = (_Float16)(asc * wrow[16 + 4 * kb + rr]);
        }
#pragma unroll
        for (int r = 0; r < 4; r++) {
            const int G = 32 * r + 16 * jj + 4 * kb + r_;
            const float bsc = (r == 2) ? P2L2E : NL2E;
            bacc1[r] = bsc * (b_ih[G] + b_hh[G]);
        }
    }

    // ---- proj A-frag (each wave owns tile p=r_; both jj groups keep a copy) ----
    f16x8 owf;
    f32x4 oacc;
    {
        const int p = r_;
        const float* row = out_W + (size_t)(16 * p + n_) * HID;
#pragma unroll
        for (int rr = 0; rr < 4; rr++) {
            owf[rr]     = (_Float16)row[4 * kb + rr];
            owf[4 + rr] = (_Float16)row[4 * kb + 16 + rr];
        }
#pragma unroll
        for (int r = 0; r < 4; r++) oacc[r] = out_b[16 * p + 4 * kb + r];
    }

    // ---- h0 = z @ init_W^T + init_b (one cell per thread: 512 = 16x32) ----
    {
        int m = tid >> 5, j = tid & 31;
        const float4* zp = (const float4*)(z + (size_t)(rbase + m) * LATENT);
        const float4* wp = (const float4*)(init_W + (size_t)j * LATENT);
        float acc = init_b[j];
#pragma unroll
        for (int k = 0; k < LATENT / 4; k++) {
            float4 a4 = zp[k], b4 = wp[k];
            acc = fmaf(a4.x, b4.x, acc); acc = fmaf(a4.y, b4.y, acc);
            acc = fmaf(a4.z, b4.z, acc); acc = fmaf(a4.w, b4.w, acc);
        }
        hst[m * LSW + j] = (_Float16)acc;
    }
    __syncthreads();

    // initial fragment: slot 4jj'+rr <- h0[n_][4kb+rr / 16+4kb+rr]
    f16x8 a;
    {
        f16x4 lo = *(const f16x4*)&hst[n_ * LSW + 4 * kb];
        f16x4 hi = *(const f16x4*)&hst[n_ * LSW + 4 * kb + 16];
#pragma unroll
        for (int r = 0; r < 4; r++) { a[r] = lo[r]; a[4 + r] = hi[r]; }
    }

    float cs = 0.f;   // 2log2e-scaled cell state of cell 4kb+16jj+r_, row n_

    float* yb = y + (size_t)(rbase + n_) * SEQ * OUT_N + 16 * r_ + 4 * kb;

    for (int t = 0; t < SEQ; t += 4) {
#pragma unroll
        for (int u = 0; u < 4; u++) {
            const int par = u & 1;
            // ---- gate MFMA first: issues the moment the exchange read lands ----
            f32x4 acc = __builtin_amdgcn_mfma_f32_16x16x32_f16(wf1, a, bacc1, 0, 0, 0);

            // ---- deferred projection: a = h_s, store y[s-1] (group jj==par) ----
            if (jj == par) {
                f32x4 py = __builtin_amdgcn_mfma_f32_16x16x32_f16(owf, a, oacc, 0, 0, 0);
                if (t + u) *(f32x4*)(yb + (size_t)(t + u - 1) * OUT_N) = py;
            }

            // ---- activation: 8 transc (both sig*tanh pairs rcp-fused) ----
            {
                float Fi  = fexp2(acc[0]);                  // e^{-x_i}
                float Ff  = fexp2(acc[1]);                  // e^{-x_f}
                float Eg  = fexp2(acc[2]);                  // e^{2 x_g}
                float Fo  = fexp2(acc[3]);                  // e^{-x_o}
                float rig = frcp((1.f + Fi) * (1.f + Eg));
                float tg  = fmaf(P2L2E, Eg, -P2L2E);        // 2L*(Eg-1)
                float ig  = tg * rig;                       // 2L*sig(i)*tanh(g)
                float gf  = frcp(1.f + Ff);                 // sig(f)
                float csn = fmaf(gf, cs, ig);               // 2L-scaled c
                cs = csn;
                float Ecs = fexp2(fminf(csn, 126.f));       // e^{2c}, overflow-safe
                float rd  = frcp((1.f + Fo) * (1.f + Ecs));
                float hh  = (Ecs - 1.f) * rd;               // sig(o)*tanh(c)
                union { _Float16 h; unsigned short u16; } cv;
                cv.h = (_Float16)hh;
                hx[par][lane][4 * jj + r_] = cv.u16;
            }
            lds_barrier();

            // ---- rebuild fragment: 4x ds_read_b32, conflict-free, slot order ----
            {
                union { unsigned uu[4]; f16x8 v; } ua;
                const unsigned* rp = (const unsigned*)&hx[par][lane][0];
                ua.uu[0] = rp[0]; ua.uu[1] = rp[1]; ua.uu[2] = rp[2]; ua.uu[3] = rp[3];
                a = ua.v;
            }
        }
    }

    // ---- tail: y[511] = proj(h_512) (jj==0 group; par of step 512 is 0) ----
    if (jj == 0) {
        f32x4 py = __builtin_amdgcn_mfma_f32_16x16x32_f16(owf, a, oacc, 0, 0, 0);
        *(f32x4*)(yb + (size_t)(SEQ - 1) * OUT_N) = py;
    }
}

extern "C" void kernel_launch(void* const* d_in, const int* in_sizes, int n_in,
                              void* d_out, int out_size, void* d_ws, size_t ws_size,
                              hipStream_t stream) {
    const float* z      = (const float*)d_in[0];
    const float* init_W = (const float*)d_in[1];
    const float* init_b = (const float*)d_in[2];
    // d_in[3] = W_ih: unused (x input is all zeros; only biases survive)
    const float* W_hh   = (const float*)d_in[4];
    const float* b_ih   = (const float*)d_in[5];
    const float* b_hh   = (const float*)d_in[6];
    const float* out_W  = (const float*)d_in[7];
    const float* out_b  = (const float*)d_in[8];
    float* yout = (float*)d_out;

    lstm_tr20<<<B_SZ / ROWS, 512, 0, stream>>>(z, init_W, init_b, W_hh, b_ih, b_hh,
                                               out_W, out_b, yout);
}